// Round 3
// baseline (955.999 us; speedup 1.0000x reference)
//
#include <hip/hip_runtime.h>
#include <stdint.h>

// Problem constants (fixed by setup_inputs)
#define CCH 64
#define HW  (1024 * 1024)
#define NPIX (1024 * 1024)
#define NSEG 4096
#define NBIN 65536          // pos >> 4 buckets (one 64B feature line per bucket)

typedef uint32_t u32x4 __attribute__((ext_vector_type(4)));

// ws layout (KB offsets):
//      0  packed        u32[NPIX]        4096 KB
//   4096  sortedPos     u32[NPIX]        4096 KB
//   8192  poshist       u32[NBIN]         256 KB   \ one contiguous 512 KB memset
//   8448  seghistPad    u32[NSEG*16]      256 KB   /
//   8704  posLocal      u32[NBIN]         256 KB
//   8960  posBlk        u32[64]             4 KB
//   8964  posBlkExc     u32[64]             4 KB
//   8968  segOff        u32[NSEG]          16 KB
//   9216  segCursorPad  u32[NSEG*16]      256 KB
//  10240  posCursorPad  u32[NBIN*16]     4096 KB
//  16384  gathered      u32[NPIX*32]   131072 KB  (bf16-pair packed rows, 128 MB)
#define WS_NEED ((size_t)147456 * 1024)

__device__ inline uint32_t pack_bf16(float a, float b) {
    uint32_t ua = __float_as_uint(a), ub = __float_as_uint(b);
    ua = (ua + 0x7FFFu + ((ua >> 16) & 1u)) >> 16;   // RNE
    ub = (ub + 0x7FFFu + ((ub >> 16) & 1u)) >> 16;
    return (ub << 16) | ua;                           // lo = ch 2k, hi = ch 2k+1
}
__device__ inline float bf_lo(uint32_t v) { return __uint_as_float(v << 16); }
__device__ inline float bf_hi(uint32_t v) { return __uint_as_float(v & 0xFFFF0000u); }

// 2 entries per thread
__global__ void k1_pack_hist(const int4* __restrict__ pix2,
                             const int2* __restrict__ seg2,
                             uint2* __restrict__ packed2,
                             uint32_t* __restrict__ poshist,
                             uint32_t* __restrict__ seghistPad) {
    int n = blockIdx.x * blockDim.x + threadIdx.x;
    int4 yx = pix2[n];                    // (y0,x0,y1,x1)
    int2 ss = seg2[n];
    uint32_t pos0 = ((uint32_t)yx.x << 10) | (uint32_t)yx.y;
    uint32_t pos1 = ((uint32_t)yx.z << 10) | (uint32_t)yx.w;
    packed2[n] = make_uint2(((uint32_t)ss.x << 20) | pos0,
                            ((uint32_t)ss.y << 20) | pos1);
    atomicAdd(&poshist[pos0 >> 4], 1u);
    atomicAdd(&poshist[pos1 >> 4], 1u);
    atomicAdd(&seghistPad[(uint32_t)ss.x * 16], 1u);
    atomicAdd(&seghistPad[(uint32_t)ss.y * 16], 1u);
}

// 64 blocks x 1024: local inclusive scan of poshist -> local EXCLUSIVE + block total
__global__ void k2a_scan_local(const uint32_t* __restrict__ poshist,
                               uint32_t* __restrict__ posLocal,
                               uint32_t* __restrict__ posBlk) {
    __shared__ uint32_t sh[1024];
    int t = threadIdx.x, b = blockIdx.x;
    int i = b * 1024 + t;
    uint32_t v = poshist[i];
    sh[t] = v;
    __syncthreads();
    for (int off = 1; off < 1024; off <<= 1) {
        uint32_t u = (t >= off) ? sh[t - off] : 0u;
        __syncthreads();
        sh[t] += u;
        __syncthreads();
    }
    uint32_t inc = sh[t];
    posLocal[i] = inc - v;
    if (t == 1023) posBlk[b] = inc;
}

// 1 block x 1024: scan 64 block totals (wave 0) + scan seghist (4 bins/thread)
__global__ void k2b_scan_tops(const uint32_t* __restrict__ posBlk,
                              uint32_t* __restrict__ posBlkExc,
                              const uint32_t* __restrict__ seghistPad,
                              uint32_t* __restrict__ segOff,
                              uint32_t* __restrict__ segCursorPad) {
    int t = threadIdx.x;
    if (t < 64) {
        uint32_t v = posBlk[t];
        uint32_t x = v;
        for (int off = 1; off < 64; off <<= 1) {
            uint32_t u = __shfl_up(x, off);
            if ((t & 63) >= off) x += u;
        }
        posBlkExc[t] = x - v;
    }
    uint32_t c0 = seghistPad[(4 * t + 0) * 16];
    uint32_t c1 = seghistPad[(4 * t + 1) * 16];
    uint32_t c2 = seghistPad[(4 * t + 2) * 16];
    uint32_t c3 = seghistPad[(4 * t + 3) * 16];
    uint32_t tot = c0 + c1 + c2 + c3;
    __shared__ uint32_t sh[1024];
    sh[t] = tot;
    __syncthreads();
    for (int off = 1; off < 1024; off <<= 1) {
        uint32_t u = (t >= off) ? sh[t - off] : 0u;
        __syncthreads();
        sh[t] += u;
        __syncthreads();
    }
    uint32_t base = sh[t] - tot;
    uint32_t o0 = base, o1 = base + c0, o2 = o1 + c1, o3 = o2 + c2;
    ((uint4*)segOff)[t] = make_uint4(o0, o1, o2, o3);
    segCursorPad[(4 * t + 0) * 16] = o0;
    segCursorPad[(4 * t + 1) * 16] = o1;
    segCursorPad[(4 * t + 2) * 16] = o2;
    segCursorPad[(4 * t + 3) * 16] = o3;
}

// 64 blocks x 1024: final cursor = local exclusive + block offset, 1 bin / 64B line
__global__ void k2c_scan_add(const uint32_t* __restrict__ posLocal,
                             const uint32_t* __restrict__ posBlkExc,
                             uint32_t* __restrict__ posCursorPad) {
    int t = threadIdx.x, b = blockIdx.x;
    int i = b * 1024 + t;
    posCursorPad[(size_t)i * 16] = posLocal[i] + posBlkExc[b];
}

// 2 entries per thread
__global__ void k3_scatter(const uint2* __restrict__ packed2,
                           uint32_t* __restrict__ posCursorPad,
                           uint32_t* __restrict__ sorted) {
    int n = blockIdx.x * blockDim.x + threadIdx.x;
    uint2 p = packed2[n];
    uint32_t d0 = atomicAdd(&posCursorPad[(size_t)((p.x & 0xFFFFFu) >> 4) * 16], 1u);
    uint32_t d1 = atomicAdd(&posCursorPad[(size_t)((p.y & 0xFFFFFu) >> 4) * 16], 1u);
    sorted[d0] = p.x;
    sorted[d1] = p.y;
}

// Main gather: one PIXEL per lane. Loads coalesced by the position sort
// (consecutive lanes = consecutive sorted entries = same feature lines).
// Row write = 8 contiguous nontemporal dwordx4 to segment-rank row.
// No LDS, no barriers -> max memory-level parallelism.
__global__ __launch_bounds__(256) void k4_gather(const float* __restrict__ feat,
                                                 const uint32_t* __restrict__ sorted,
                                                 uint32_t* __restrict__ segCursorPad,
                                                 uint32_t* __restrict__ gathered) {
    int idx = blockIdx.x * blockDim.x + threadIdx.x;
    uint32_t pk = sorted[idx];
    uint32_t sg = pk >> 20;
    const float* fp = feat + (pk & 0xFFFFFu);
    uint32_t r = atomicAdd(&segCursorPad[sg * 16], 1u);
    u32x4* dst = (u32x4*)(gathered + (size_t)r * 32);
#pragma unroll
    for (int j = 0; j < 8; ++j) {
        float a0 = fp[(size_t)(8 * j + 0) * HW];
        float b0 = fp[(size_t)(8 * j + 1) * HW];
        float a1 = fp[(size_t)(8 * j + 2) * HW];
        float b1 = fp[(size_t)(8 * j + 3) * HW];
        float a2 = fp[(size_t)(8 * j + 4) * HW];
        float b2 = fp[(size_t)(8 * j + 5) * HW];
        float a3 = fp[(size_t)(8 * j + 6) * HW];
        float b3 = fp[(size_t)(8 * j + 7) * HW];
        u32x4 v = { pack_bf16(a0, b0), pack_bf16(a1, b1),
                    pack_bf16(a2, b2), pack_bf16(a3, b3) };
        __builtin_nontemporal_store(v, dst + j);
    }
}

// One block per segment: stream contiguous rows, reduce, divide, store.
__global__ __launch_bounds__(256) void k5_reduce(const uint32_t* __restrict__ gathered,
                                                 const uint32_t* __restrict__ segOff,
                                                 const uint32_t* __restrict__ seghistPad,
                                                 float* __restrict__ out) {
    const int s = blockIdx.x;
    const int tid = threadIdx.x;
    const int k = tid & 31;        // chan-pair
    const int sub = tid >> 5;      // 0..7 row-group
    uint32_t base = segOff[s];
    uint32_t cnt = seghistPad[s * 16];
    float a0 = 0.f, a1 = 0.f;
    for (uint32_t r = sub; r < cnt; r += 8) {
        uint32_t v = __builtin_nontemporal_load(&gathered[(size_t)(base + r) * 32 + k]);
        a0 += bf_lo(v);
        a1 += bf_hi(v);
    }
    __shared__ float red0[8][32];
    __shared__ float red1[8][32];
    red0[sub][k] = a0;
    red1[sub][k] = a1;
    __syncthreads();
    if (tid < 32) {
        float s0 = 0.f, s1 = 0.f;
#pragma unroll
        for (int j = 0; j < 8; ++j) { s0 += red0[j][tid]; s1 += red1[j][tid]; }
        float inv = 1.0f / (float)(cnt ? cnt : 1u);
        ((float2*)out)[s * 32 + tid] = make_float2(s0 * inv, s1 * inv);
    }
}

// ---------- fallback path (small ws): direct-atomic kernel ----------
__global__ __launch_bounds__(256) void k4_stream(const float* __restrict__ feat,
                                                 const uint32_t* __restrict__ sorted,
                                                 float* __restrict__ sums) {
    __shared__ float tile[64 * 65];
    __shared__ uint32_t epack[1024];
    const int tid = threadIdx.x;
    const int w = tid >> 6;
    const int l = tid & 63;
    const int base = blockIdx.x * 1024;
    for (int i = tid; i < 1024; i += 256) epack[i] = sorted[base + i];
    __syncthreads();
    for (int t = 0; t < 16; ++t) {
        uint32_t pk = epack[t * 64 + l];
        const float* fp = feat + (pk & 0xFFFFFu);
#pragma unroll
        for (int cc = 0; cc < 16; ++cc) {
            int c = (w << 4) + cc;
            tile[l * 65 + c] = fp[(size_t)c * HW];
        }
        __syncthreads();
#pragma unroll
        for (int pp = 0; pp < 16; ++pp) {
            int p = (w << 4) + pp;
            uint32_t sg = epack[t * 64 + p] >> 20;
            atomicAdd(&sums[sg * 64 + l], tile[p * 65 + l]);
        }
        __syncthreads();
    }
}

__global__ void k5_div(float* __restrict__ out, const uint32_t* __restrict__ seghistPad) {
    int i = blockIdx.x * blockDim.x + threadIdx.x;
    uint32_t cnt = seghistPad[(i >> 6) * 16];
    float c = (float)(cnt ? cnt : 1u);
    out[i] = out[i] / c;
}

extern "C" void kernel_launch(void* const* d_in, const int* in_sizes, int n_in,
                              void* d_out, int out_size, void* d_ws, size_t ws_size,
                              hipStream_t stream) {
    const float* feat = (const float*)d_in[0];
    const int*   pix  = (const int*)d_in[1];
    const int*   seg  = (const int*)d_in[2];
    float* out = (float*)d_out;

    uint8_t* ws = (uint8_t*)d_ws;
    uint32_t* packed       = (uint32_t*)(ws);
    uint32_t* sortedPos    = (uint32_t*)(ws + (size_t)4096 * 1024);
    uint32_t* poshist      = (uint32_t*)(ws + (size_t)8192 * 1024);
    uint32_t* seghistPad   = (uint32_t*)(ws + (size_t)8448 * 1024);
    uint32_t* posLocal     = (uint32_t*)(ws + (size_t)8704 * 1024);
    uint32_t* posBlk       = (uint32_t*)(ws + (size_t)8960 * 1024);
    uint32_t* posBlkExc    = (uint32_t*)(ws + (size_t)8964 * 1024);
    uint32_t* segOff       = (uint32_t*)(ws + (size_t)8968 * 1024);
    uint32_t* segCursorPad = (uint32_t*)(ws + (size_t)9216 * 1024);
    uint32_t* posCursorPad = (uint32_t*)(ws + (size_t)10240 * 1024);
    uint32_t* gathered     = (uint32_t*)(ws + (size_t)16384 * 1024);

    hipMemsetAsync(poshist, 0, (size_t)512 * 1024, stream);   // poshist + seghistPad
    hipMemsetAsync(out, 0, (size_t)NSEG * CCH * sizeof(float), stream);

    k1_pack_hist<<<NPIX / 512, 256, 0, stream>>>((const int4*)pix, (const int2*)seg,
                                                 (uint2*)packed, poshist, seghistPad);
    k2a_scan_local<<<64, 1024, 0, stream>>>(poshist, posLocal, posBlk);
    k2b_scan_tops<<<1, 1024, 0, stream>>>(posBlk, posBlkExc, seghistPad, segOff, segCursorPad);
    k2c_scan_add<<<64, 1024, 0, stream>>>(posLocal, posBlkExc, posCursorPad);
    k3_scatter<<<NPIX / 512, 256, 0, stream>>>((const uint2*)packed, posCursorPad, sortedPos);

    if (ws_size >= WS_NEED) {
        k4_gather<<<NPIX / 256, 256, 0, stream>>>(feat, sortedPos, segCursorPad, gathered);
        k5_reduce<<<NSEG, 256, 0, stream>>>(gathered, segOff, seghistPad, out);
    } else {
        k4_stream<<<NPIX / 1024, 256, 0, stream>>>(feat, sortedPos, out);
        k5_div<<<(NSEG * CCH) / 256, 256, 0, stream>>>(out, seghistPad);
    }
}

// Round 4
// 626.026 us; speedup vs baseline: 1.5271x; 1.5271x over previous
//
#include <hip/hip_runtime.h>
#include <stdint.h>

// Problem constants (fixed by setup_inputs)
#define CCH 64
#define HW  (1024 * 1024)
#define NPIX (1024 * 1024)
#define NSEG 4096
#define NBIN 65536          // pos >> 4 buckets (one 64B feature line per bucket)

typedef uint32_t u32x4 __attribute__((ext_vector_type(4)));

// ws layout (KB offsets):
//      0  packed        u32[NPIX]        4096 KB
//   4096  sortedPos     u32[NPIX]        4096 KB
//   8192  poshist       u32[NBIN]         256 KB   \ one contiguous 512 KB memset
//   8448  seghistPad    u32[NSEG*16]      256 KB   /
//   8704  posLocal      u32[NBIN]         256 KB
//   8960  posBlk        u32[64]             4 KB
//   8964  posBlkExc     u32[64]             4 KB
//   8968  segOff        u32[NSEG]          16 KB
//   9216  segCursorPad  u32[NSEG*16]      256 KB
//  10240  posCursorPad  u32[NBIN*16]     4096 KB
//  16384  gathered      u32[NPIX*32]   131072 KB  (bf16-pair packed rows, 128 MB)
#define WS_NEED ((size_t)147456 * 1024)

__device__ inline uint32_t pack_bf16(float a, float b) {
    uint32_t ua = __float_as_uint(a), ub = __float_as_uint(b);
    ua = (ua + 0x7FFFu + ((ua >> 16) & 1u)) >> 16;   // RNE
    ub = (ub + 0x7FFFu + ((ub >> 16) & 1u)) >> 16;
    return (ub << 16) | ua;                           // lo = ch 2k, hi = ch 2k+1
}
__device__ inline float bf_lo(uint32_t v) { return __uint_as_float(v << 16); }
__device__ inline float bf_hi(uint32_t v) { return __uint_as_float(v & 0xFFFF0000u); }

// 2 entries per thread
__global__ void k1_pack_hist(const int4* __restrict__ pix2,
                             const int2* __restrict__ seg2,
                             uint2* __restrict__ packed2,
                             uint32_t* __restrict__ poshist,
                             uint32_t* __restrict__ seghistPad) {
    int n = blockIdx.x * blockDim.x + threadIdx.x;
    int4 yx = pix2[n];                    // (y0,x0,y1,x1)
    int2 ss = seg2[n];
    uint32_t pos0 = ((uint32_t)yx.x << 10) | (uint32_t)yx.y;
    uint32_t pos1 = ((uint32_t)yx.z << 10) | (uint32_t)yx.w;
    packed2[n] = make_uint2(((uint32_t)ss.x << 20) | pos0,
                            ((uint32_t)ss.y << 20) | pos1);
    atomicAdd(&poshist[pos0 >> 4], 1u);
    atomicAdd(&poshist[pos1 >> 4], 1u);
    atomicAdd(&seghistPad[(uint32_t)ss.x * 16], 1u);
    atomicAdd(&seghistPad[(uint32_t)ss.y * 16], 1u);
}

// 64 blocks x 1024: local inclusive scan of poshist -> local EXCLUSIVE + block total
__global__ void k2a_scan_local(const uint32_t* __restrict__ poshist,
                               uint32_t* __restrict__ posLocal,
                               uint32_t* __restrict__ posBlk) {
    __shared__ uint32_t sh[1024];
    int t = threadIdx.x, b = blockIdx.x;
    int i = b * 1024 + t;
    uint32_t v = poshist[i];
    sh[t] = v;
    __syncthreads();
    for (int off = 1; off < 1024; off <<= 1) {
        uint32_t u = (t >= off) ? sh[t - off] : 0u;
        __syncthreads();
        sh[t] += u;
        __syncthreads();
    }
    uint32_t inc = sh[t];
    posLocal[i] = inc - v;
    if (t == 1023) posBlk[b] = inc;
}

// 1 block x 1024: scan 64 block totals (wave 0) + scan seghist (4 bins/thread)
__global__ void k2b_scan_tops(const uint32_t* __restrict__ posBlk,
                              uint32_t* __restrict__ posBlkExc,
                              const uint32_t* __restrict__ seghistPad,
                              uint32_t* __restrict__ segOff,
                              uint32_t* __restrict__ segCursorPad) {
    int t = threadIdx.x;
    if (t < 64) {
        uint32_t v = posBlk[t];
        uint32_t x = v;
        for (int off = 1; off < 64; off <<= 1) {
            uint32_t u = __shfl_up(x, off);
            if ((t & 63) >= off) x += u;
        }
        posBlkExc[t] = x - v;
    }
    uint32_t c0 = seghistPad[(4 * t + 0) * 16];
    uint32_t c1 = seghistPad[(4 * t + 1) * 16];
    uint32_t c2 = seghistPad[(4 * t + 2) * 16];
    uint32_t c3 = seghistPad[(4 * t + 3) * 16];
    uint32_t tot = c0 + c1 + c2 + c3;
    __shared__ uint32_t sh[1024];
    sh[t] = tot;
    __syncthreads();
    for (int off = 1; off < 1024; off <<= 1) {
        uint32_t u = (t >= off) ? sh[t - off] : 0u;
        __syncthreads();
        sh[t] += u;
        __syncthreads();
    }
    uint32_t base = sh[t] - tot;
    uint32_t o0 = base, o1 = base + c0, o2 = o1 + c1, o3 = o2 + c2;
    ((uint4*)segOff)[t] = make_uint4(o0, o1, o2, o3);
    segCursorPad[(4 * t + 0) * 16] = o0;
    segCursorPad[(4 * t + 1) * 16] = o1;
    segCursorPad[(4 * t + 2) * 16] = o2;
    segCursorPad[(4 * t + 3) * 16] = o3;
}

// 64 blocks x 1024: final cursor = local exclusive + block offset, 1 bin / 64B line
__global__ void k2c_scan_add(const uint32_t* __restrict__ posLocal,
                             const uint32_t* __restrict__ posBlkExc,
                             uint32_t* __restrict__ posCursorPad) {
    int t = threadIdx.x, b = blockIdx.x;
    int i = b * 1024 + t;
    posCursorPad[(size_t)i * 16] = posLocal[i] + posBlkExc[b];
}

// 2 entries per thread
__global__ void k3_scatter(const uint2* __restrict__ packed2,
                           uint32_t* __restrict__ posCursorPad,
                           uint32_t* __restrict__ sorted) {
    int n = blockIdx.x * blockDim.x + threadIdx.x;
    uint2 p = packed2[n];
    uint32_t d0 = atomicAdd(&posCursorPad[(size_t)((p.x & 0xFFFFFu) >> 4) * 16], 1u);
    uint32_t d1 = atomicAdd(&posCursorPad[(size_t)((p.y & 0xFFFFFu) >> 4) * 16], 1u);
    sorted[d0] = p.x;
    sorted[d1] = p.y;
}

// Main gather: one pixel per lane, 64 scalar loads in flight (coalesced by the
// position sort), pack to bf16 pairs, ONE LDS transpose (stride 36 u32 -> uniform
// bank mapping both phases), then 8-lanes-per-row stores: each instruction writes
// 8 fully-covered 128B rows (vs R3's 64 scattered 16B chunks -> 2.4x write amp).
__global__ __launch_bounds__(256) void k4_gather(const float* __restrict__ feat,
                                                 const uint32_t* __restrict__ sorted,
                                                 uint32_t* __restrict__ segCursorPad,
                                                 uint32_t* __restrict__ gathered) {
    __shared__ uint32_t tile[256 * 36];   // [pixel][chan-pair], stride 36 (144B, 16B-aligned)
    __shared__ uint32_t rnk[256];
    const int tid = threadIdx.x;
    const int idx = blockIdx.x * 256 + tid;

    uint32_t pk = sorted[idx];
    uint32_t sg = pk >> 20;
    const float* fp = feat + (pk & 0xFFFFFu);
    rnk[tid] = atomicAdd(&segCursorPad[sg * 16], 1u);

#pragma unroll
    for (int j = 0; j < 8; ++j) {
        float a0 = fp[(size_t)(8 * j + 0) * HW];
        float b0 = fp[(size_t)(8 * j + 1) * HW];
        float a1 = fp[(size_t)(8 * j + 2) * HW];
        float b1 = fp[(size_t)(8 * j + 3) * HW];
        float a2 = fp[(size_t)(8 * j + 4) * HW];
        float b2 = fp[(size_t)(8 * j + 5) * HW];
        float a3 = fp[(size_t)(8 * j + 6) * HW];
        float b3 = fp[(size_t)(8 * j + 7) * HW];
        u32x4 v = { pack_bf16(a0, b0), pack_bf16(a1, b1),
                    pack_bf16(a2, b2), pack_bf16(a3, b3) };
        *(u32x4*)&tile[tid * 36 + j * 4] = v;
    }
    __syncthreads();

    const int sub = tid & 7;        // 16B chunk within row
    const int rg  = tid >> 3;       // row group 0..31
#pragma unroll
    for (int it = 0; it < 8; ++it) {
        int row = it * 32 + rg;
        uint32_t r = rnk[row];
        u32x4 v = *(const u32x4*)&tile[row * 36 + sub * 4];
        __builtin_nontemporal_store(v, (u32x4*)(gathered + (size_t)r * 32 + sub * 4));
    }
}

// One block per segment: stream contiguous rows, reduce, divide, store.
__global__ __launch_bounds__(256) void k5_reduce(const uint32_t* __restrict__ gathered,
                                                 const uint32_t* __restrict__ segOff,
                                                 const uint32_t* __restrict__ seghistPad,
                                                 float* __restrict__ out) {
    const int s = blockIdx.x;
    const int tid = threadIdx.x;
    const int k = tid & 31;        // chan-pair
    const int sub = tid >> 5;      // 0..7 row-group
    uint32_t base = segOff[s];
    uint32_t cnt = seghistPad[s * 16];
    float a0 = 0.f, a1 = 0.f;
    for (uint32_t r = sub; r < cnt; r += 8) {
        uint32_t v = __builtin_nontemporal_load(&gathered[(size_t)(base + r) * 32 + k]);
        a0 += bf_lo(v);
        a1 += bf_hi(v);
    }
    __shared__ float red0[8][32];
    __shared__ float red1[8][32];
    red0[sub][k] = a0;
    red1[sub][k] = a1;
    __syncthreads();
    if (tid < 32) {
        float s0 = 0.f, s1 = 0.f;
#pragma unroll
        for (int j = 0; j < 8; ++j) { s0 += red0[j][tid]; s1 += red1[j][tid]; }
        float inv = 1.0f / (float)(cnt ? cnt : 1u);
        ((float2*)out)[s * 32 + tid] = make_float2(s0 * inv, s1 * inv);
    }
}

// ---------- fallback path (small ws): direct-atomic kernel ----------
__global__ __launch_bounds__(256) void k4_stream(const float* __restrict__ feat,
                                                 const uint32_t* __restrict__ sorted,
                                                 float* __restrict__ sums) {
    __shared__ float tile[64 * 65];
    __shared__ uint32_t epack[1024];
    const int tid = threadIdx.x;
    const int w = tid >> 6;
    const int l = tid & 63;
    const int base = blockIdx.x * 1024;
    for (int i = tid; i < 1024; i += 256) epack[i] = sorted[base + i];
    __syncthreads();
    for (int t = 0; t < 16; ++t) {
        uint32_t pk = epack[t * 64 + l];
        const float* fp = feat + (pk & 0xFFFFFu);
#pragma unroll
        for (int cc = 0; cc < 16; ++cc) {
            int c = (w << 4) + cc;
            tile[l * 65 + c] = fp[(size_t)c * HW];
        }
        __syncthreads();
#pragma unroll
        for (int pp = 0; pp < 16; ++pp) {
            int p = (w << 4) + pp;
            uint32_t sg = epack[t * 64 + p] >> 20;
            atomicAdd(&sums[sg * 64 + l], tile[p * 65 + l]);
        }
        __syncthreads();
    }
}

__global__ void k5_div(float* __restrict__ out, const uint32_t* __restrict__ seghistPad) {
    int i = blockIdx.x * blockDim.x + threadIdx.x;
    uint32_t cnt = seghistPad[(i >> 6) * 16];
    float c = (float)(cnt ? cnt : 1u);
    out[i] = out[i] / c;
}

extern "C" void kernel_launch(void* const* d_in, const int* in_sizes, int n_in,
                              void* d_out, int out_size, void* d_ws, size_t ws_size,
                              hipStream_t stream) {
    const float* feat = (const float*)d_in[0];
    const int*   pix  = (const int*)d_in[1];
    const int*   seg  = (const int*)d_in[2];
    float* out = (float*)d_out;

    uint8_t* ws = (uint8_t*)d_ws;
    uint32_t* packed       = (uint32_t*)(ws);
    uint32_t* sortedPos    = (uint32_t*)(ws + (size_t)4096 * 1024);
    uint32_t* poshist      = (uint32_t*)(ws + (size_t)8192 * 1024);
    uint32_t* seghistPad   = (uint32_t*)(ws + (size_t)8448 * 1024);
    uint32_t* posLocal     = (uint32_t*)(ws + (size_t)8704 * 1024);
    uint32_t* posBlk       = (uint32_t*)(ws + (size_t)8960 * 1024);
    uint32_t* posBlkExc    = (uint32_t*)(ws + (size_t)8964 * 1024);
    uint32_t* segOff       = (uint32_t*)(ws + (size_t)8968 * 1024);
    uint32_t* segCursorPad = (uint32_t*)(ws + (size_t)9216 * 1024);
    uint32_t* posCursorPad = (uint32_t*)(ws + (size_t)10240 * 1024);
    uint32_t* gathered     = (uint32_t*)(ws + (size_t)16384 * 1024);

    hipMemsetAsync(poshist, 0, (size_t)512 * 1024, stream);   // poshist + seghistPad
    hipMemsetAsync(out, 0, (size_t)NSEG * CCH * sizeof(float), stream);

    k1_pack_hist<<<NPIX / 512, 256, 0, stream>>>((const int4*)pix, (const int2*)seg,
                                                 (uint2*)packed, poshist, seghistPad);
    k2a_scan_local<<<64, 1024, 0, stream>>>(poshist, posLocal, posBlk);
    k2b_scan_tops<<<1, 1024, 0, stream>>>(posBlk, posBlkExc, seghistPad, segOff, segCursorPad);
    k2c_scan_add<<<64, 1024, 0, stream>>>(posLocal, posBlkExc, posCursorPad);
    k3_scatter<<<NPIX / 512, 256, 0, stream>>>((const uint2*)packed, posCursorPad, sortedPos);

    if (ws_size >= WS_NEED) {
        k4_gather<<<NPIX / 256, 256, 0, stream>>>(feat, sortedPos, segCursorPad, gathered);
        k5_reduce<<<NSEG, 256, 0, stream>>>(gathered, segOff, seghistPad, out);
    } else {
        k4_stream<<<NPIX / 1024, 256, 0, stream>>>(feat, sortedPos, out);
        k5_div<<<(NSEG * CCH) / 256, 256, 0, stream>>>(out, seghistPad);
    }
}

// Round 5
// 604.253 us; speedup vs baseline: 1.5821x; 1.0360x over previous
//
#include <hip/hip_runtime.h>
#include <stdint.h>

// Problem constants (fixed by setup_inputs)
#define CCH 64
#define HW  (1024 * 1024)
#define NPIX (1024 * 1024)
#define NSEG 4096
#define NBIN 65536          // pos >> 4 buckets (one 64B feature line per bucket)

typedef uint32_t u32x4 __attribute__((ext_vector_type(4)));

// ws layout (KB offsets):
//      0  packed        u32[NPIX]        4096 KB
//   4096  sortedPos     u32[NPIX]        4096 KB
//   8192  poshist       u32[NBIN]         256 KB   \ one contiguous 512 KB memset
//   8448  seghistPad    u32[NSEG*16]      256 KB   /
//   8704  posLocal      u32[NBIN]         256 KB
//   8960  posBlk        u32[64]             4 KB
//   8964  posBlkExc     u32[64]             4 KB
//   8968  segOff        u32[NSEG]          16 KB
//   9216  segCursorPad  u32[NSEG*16]      256 KB
//  10240  posCursorPad  u32[NBIN*16]     4096 KB
//  16384  gathered      u32[NPIX*32]   131072 KB  (bf16-pair packed rows, 128 MB)
#define WS_NEED ((size_t)147456 * 1024)

__device__ inline uint32_t pack_bf16(float a, float b) {
    uint32_t ua = __float_as_uint(a), ub = __float_as_uint(b);
    ua = (ua + 0x7FFFu + ((ua >> 16) & 1u)) >> 16;   // RNE
    ub = (ub + 0x7FFFu + ((ub >> 16) & 1u)) >> 16;
    return (ub << 16) | ua;                           // lo = ch 2k, hi = ch 2k+1
}
__device__ inline float bf_lo(uint32_t v) { return __uint_as_float(v << 16); }
__device__ inline float bf_hi(uint32_t v) { return __uint_as_float(v & 0xFFFF0000u); }

// 2 entries per thread
__global__ void k1_pack_hist(const int4* __restrict__ pix2,
                             const int2* __restrict__ seg2,
                             uint2* __restrict__ packed2,
                             uint32_t* __restrict__ poshist,
                             uint32_t* __restrict__ seghistPad) {
    int n = blockIdx.x * blockDim.x + threadIdx.x;
    int4 yx = pix2[n];                    // (y0,x0,y1,x1)
    int2 ss = seg2[n];
    uint32_t pos0 = ((uint32_t)yx.x << 10) | (uint32_t)yx.y;
    uint32_t pos1 = ((uint32_t)yx.z << 10) | (uint32_t)yx.w;
    packed2[n] = make_uint2(((uint32_t)ss.x << 20) | pos0,
                            ((uint32_t)ss.y << 20) | pos1);
    atomicAdd(&poshist[pos0 >> 4], 1u);
    atomicAdd(&poshist[pos1 >> 4], 1u);
    atomicAdd(&seghistPad[(uint32_t)ss.x * 16], 1u);
    atomicAdd(&seghistPad[(uint32_t)ss.y * 16], 1u);
}

// 64 blocks x 1024: local inclusive scan of poshist -> local EXCLUSIVE + block total
__global__ void k2a_scan_local(const uint32_t* __restrict__ poshist,
                               uint32_t* __restrict__ posLocal,
                               uint32_t* __restrict__ posBlk) {
    __shared__ uint32_t sh[1024];
    int t = threadIdx.x, b = blockIdx.x;
    int i = b * 1024 + t;
    uint32_t v = poshist[i];
    sh[t] = v;
    __syncthreads();
    for (int off = 1; off < 1024; off <<= 1) {
        uint32_t u = (t >= off) ? sh[t - off] : 0u;
        __syncthreads();
        sh[t] += u;
        __syncthreads();
    }
    uint32_t inc = sh[t];
    posLocal[i] = inc - v;
    if (t == 1023) posBlk[b] = inc;
}

// 1 block x 1024: scan 64 block totals (wave 0) + scan seghist (4 bins/thread)
__global__ void k2b_scan_tops(const uint32_t* __restrict__ posBlk,
                              uint32_t* __restrict__ posBlkExc,
                              const uint32_t* __restrict__ seghistPad,
                              uint32_t* __restrict__ segOff,
                              uint32_t* __restrict__ segCursorPad) {
    int t = threadIdx.x;
    if (t < 64) {
        uint32_t v = posBlk[t];
        uint32_t x = v;
        for (int off = 1; off < 64; off <<= 1) {
            uint32_t u = __shfl_up(x, off);
            if ((t & 63) >= off) x += u;
        }
        posBlkExc[t] = x - v;
    }
    uint32_t c0 = seghistPad[(4 * t + 0) * 16];
    uint32_t c1 = seghistPad[(4 * t + 1) * 16];
    uint32_t c2 = seghistPad[(4 * t + 2) * 16];
    uint32_t c3 = seghistPad[(4 * t + 3) * 16];
    uint32_t tot = c0 + c1 + c2 + c3;
    __shared__ uint32_t sh[1024];
    sh[t] = tot;
    __syncthreads();
    for (int off = 1; off < 1024; off <<= 1) {
        uint32_t u = (t >= off) ? sh[t - off] : 0u;
        __syncthreads();
        sh[t] += u;
        __syncthreads();
    }
    uint32_t base = sh[t] - tot;
    uint32_t o0 = base, o1 = base + c0, o2 = o1 + c1, o3 = o2 + c2;
    ((uint4*)segOff)[t] = make_uint4(o0, o1, o2, o3);
    segCursorPad[(4 * t + 0) * 16] = o0;
    segCursorPad[(4 * t + 1) * 16] = o1;
    segCursorPad[(4 * t + 2) * 16] = o2;
    segCursorPad[(4 * t + 3) * 16] = o3;
}

// 64 blocks x 1024: final cursor = local exclusive + block offset, 1 bin / 64B line
__global__ void k2c_scan_add(const uint32_t* __restrict__ posLocal,
                             const uint32_t* __restrict__ posBlkExc,
                             uint32_t* __restrict__ posCursorPad) {
    int t = threadIdx.x, b = blockIdx.x;
    int i = b * 1024 + t;
    posCursorPad[(size_t)i * 16] = posLocal[i] + posBlkExc[b];
}

// 2 entries per thread
__global__ void k3_scatter(const uint2* __restrict__ packed2,
                           uint32_t* __restrict__ posCursorPad,
                           uint32_t* __restrict__ sorted) {
    int n = blockIdx.x * blockDim.x + threadIdx.x;
    uint2 p = packed2[n];
    uint32_t d0 = atomicAdd(&posCursorPad[(size_t)((p.x & 0xFFFFFu) >> 4) * 16], 1u);
    uint32_t d1 = atomicAdd(&posCursorPad[(size_t)((p.y & 0xFFFFFu) >> 4) * 16], 1u);
    sorted[d0] = p.x;
    sorted[d1] = p.y;
}

// Main gather. MLP-first structure: all 64 plane loads issued into a register
// array BEFORE any pack/LDS op (64 outstanding vector loads/lane = vmcnt cap),
// then pack bf16 pairs -> LDS (stride 36: 16B-aligned rows, even bank spread),
// then 8-lanes-per-row coalesced nontemporal stores (full 128B rows).
__global__ __launch_bounds__(256) void k4_gather(const float* __restrict__ feat,
                                                 const uint32_t* __restrict__ sorted,
                                                 uint32_t* __restrict__ segCursorPad,
                                                 uint32_t* __restrict__ gathered) {
    __shared__ uint32_t tile[256 * 36];
    __shared__ uint32_t rnk[256];
    const int tid = threadIdx.x;
    const int idx = blockIdx.x * 256 + tid;

    uint32_t pk = sorted[idx];
    const float* fp = feat + (pk & 0xFFFFFu);
    rnk[tid] = atomicAdd(&segCursorPad[(pk >> 20) * 16], 1u);

    float v[64];
#pragma unroll
    for (int c = 0; c < 64; ++c) {
        v[c] = fp[(size_t)c * HW];        // independent: compiler keeps them in flight
    }
#pragma unroll
    for (int j = 0; j < 8; ++j) {
        u32x4 q = { pack_bf16(v[8 * j + 0], v[8 * j + 1]),
                    pack_bf16(v[8 * j + 2], v[8 * j + 3]),
                    pack_bf16(v[8 * j + 4], v[8 * j + 5]),
                    pack_bf16(v[8 * j + 6], v[8 * j + 7]) };
        *(u32x4*)&tile[tid * 36 + j * 4] = q;
    }
    __syncthreads();

    const int sub = tid & 7;        // 16B chunk within row
    const int rg  = tid >> 3;       // row group 0..31
#pragma unroll
    for (int it = 0; it < 8; ++it) {
        int row = it * 32 + rg;
        uint32_t r = rnk[row];
        u32x4 q = *(const u32x4*)&tile[row * 36 + sub * 4];
        __builtin_nontemporal_store(q, (u32x4*)(gathered + (size_t)r * 32 + sub * 4));
    }
}

// One block per segment: stream contiguous rows with u32x4 loads, reduce, divide.
__global__ __launch_bounds__(256) void k5_reduce(const uint32_t* __restrict__ gathered,
                                                 const uint32_t* __restrict__ segOff,
                                                 const uint32_t* __restrict__ seghistPad,
                                                 float* __restrict__ out) {
    const int s = blockIdx.x;
    const int tid = threadIdx.x;
    const int ch = tid & 7;        // 16B chunk (channels 8ch..8ch+7)
    const int rg = tid >> 3;       // row-group 0..31
    uint32_t base = segOff[s];
    uint32_t cnt = seghistPad[s * 16];
    float acc[8] = {0.f, 0.f, 0.f, 0.f, 0.f, 0.f, 0.f, 0.f};
    const u32x4* g4 = (const u32x4*)gathered;
    for (uint32_t r = rg; r < cnt; r += 32) {
        u32x4 v = __builtin_nontemporal_load(&g4[(size_t)(base + r) * 8 + ch]);
        acc[0] += bf_lo(v.x); acc[1] += bf_hi(v.x);
        acc[2] += bf_lo(v.y); acc[3] += bf_hi(v.y);
        acc[4] += bf_lo(v.z); acc[5] += bf_hi(v.z);
        acc[6] += bf_lo(v.w); acc[7] += bf_hi(v.w);
    }
    __shared__ float red[256][8];
#pragma unroll
    for (int j = 0; j < 8; ++j) red[tid][j] = acc[j];
    __syncthreads();
    if (tid < 64) {                 // thread = channel
        int chunk = tid >> 3, j = tid & 7;
        float sum = 0.f;
#pragma unroll
        for (int g = 0; g < 32; ++g) sum += red[g * 8 + chunk][j];
        float inv = 1.0f / (float)(cnt ? cnt : 1u);
        out[s * 64 + tid] = sum * inv;
    }
}

// ---------- fallback path (small ws): direct-atomic kernel ----------
__global__ __launch_bounds__(256) void k4_stream(const float* __restrict__ feat,
                                                 const uint32_t* __restrict__ sorted,
                                                 float* __restrict__ sums) {
    __shared__ float tile[64 * 65];
    __shared__ uint32_t epack[1024];
    const int tid = threadIdx.x;
    const int w = tid >> 6;
    const int l = tid & 63;
    const int base = blockIdx.x * 1024;
    for (int i = tid; i < 1024; i += 256) epack[i] = sorted[base + i];
    __syncthreads();
    for (int t = 0; t < 16; ++t) {
        uint32_t pk = epack[t * 64 + l];
        const float* fp = feat + (pk & 0xFFFFFu);
#pragma unroll
        for (int cc = 0; cc < 16; ++cc) {
            int c = (w << 4) + cc;
            tile[l * 65 + c] = fp[(size_t)c * HW];
        }
        __syncthreads();
#pragma unroll
        for (int pp = 0; pp < 16; ++pp) {
            int p = (w << 4) + pp;
            uint32_t sg = epack[t * 64 + p] >> 20;
            atomicAdd(&sums[sg * 64 + l], tile[p * 65 + l]);
        }
        __syncthreads();
    }
}

__global__ void k5_div(float* __restrict__ out, const uint32_t* __restrict__ seghistPad) {
    int i = blockIdx.x * blockDim.x + threadIdx.x;
    uint32_t cnt = seghistPad[(i >> 6) * 16];
    float c = (float)(cnt ? cnt : 1u);
    out[i] = out[i] / c;
}

extern "C" void kernel_launch(void* const* d_in, const int* in_sizes, int n_in,
                              void* d_out, int out_size, void* d_ws, size_t ws_size,
                              hipStream_t stream) {
    const float* feat = (const float*)d_in[0];
    const int*   pix  = (const int*)d_in[1];
    const int*   seg  = (const int*)d_in[2];
    float* out = (float*)d_out;

    uint8_t* ws = (uint8_t*)d_ws;
    uint32_t* packed       = (uint32_t*)(ws);
    uint32_t* sortedPos    = (uint32_t*)(ws + (size_t)4096 * 1024);
    uint32_t* poshist      = (uint32_t*)(ws + (size_t)8192 * 1024);
    uint32_t* seghistPad   = (uint32_t*)(ws + (size_t)8448 * 1024);
    uint32_t* posLocal     = (uint32_t*)(ws + (size_t)8704 * 1024);
    uint32_t* posBlk       = (uint32_t*)(ws + (size_t)8960 * 1024);
    uint32_t* posBlkExc    = (uint32_t*)(ws + (size_t)8964 * 1024);
    uint32_t* segOff       = (uint32_t*)(ws + (size_t)8968 * 1024);
    uint32_t* segCursorPad = (uint32_t*)(ws + (size_t)9216 * 1024);
    uint32_t* posCursorPad = (uint32_t*)(ws + (size_t)10240 * 1024);
    uint32_t* gathered     = (uint32_t*)(ws + (size_t)16384 * 1024);

    hipMemsetAsync(poshist, 0, (size_t)512 * 1024, stream);   // poshist + seghistPad

    k1_pack_hist<<<NPIX / 512, 256, 0, stream>>>((const int4*)pix, (const int2*)seg,
                                                 (uint2*)packed, poshist, seghistPad);
    k2a_scan_local<<<64, 1024, 0, stream>>>(poshist, posLocal, posBlk);
    k2b_scan_tops<<<1, 1024, 0, stream>>>(posBlk, posBlkExc, seghistPad, segOff, segCursorPad);
    k2c_scan_add<<<64, 1024, 0, stream>>>(posLocal, posBlkExc, posCursorPad);
    k3_scatter<<<NPIX / 512, 256, 0, stream>>>((const uint2*)packed, posCursorPad, sortedPos);

    if (ws_size >= WS_NEED) {
        // k5_reduce fully overwrites out -> no out memset needed on this path
        k4_gather<<<NPIX / 256, 256, 0, stream>>>(feat, sortedPos, segCursorPad, gathered);
        k5_reduce<<<NSEG, 256, 0, stream>>>(gathered, segOff, seghistPad, out);
    } else {
        hipMemsetAsync(out, 0, (size_t)NSEG * CCH * sizeof(float), stream);
        k4_stream<<<NPIX / 1024, 256, 0, stream>>>(feat, sortedPos, out);
        k5_div<<<(NSEG * CCH) / 256, 256, 0, stream>>>(out, seghistPad);
    }
}